// Round 19
// baseline (232.032 us; speedup 1.0000x reference)
//
#include <hip/hip_runtime.h>
#include <cmath>

// CXLoss pipeline, revision 19: S stored TRANSPOSED (S^T[q][p], bf16) with
// packed ushort4 (8B) stores — the C/D layout gives each lane 4 consecutive
// p-rows per reg group at fixed q, so the gemm epilogue emits 4x fewer,
// 4x wider stores than R18's 2B scatter. Passes flip orientation:
//   pass1: Wsum per q — reads S^T rows contiguously; whole p-range per wave
//          => writes gamma/beta directly (k_gb eliminated).
//   pass2: maxv per p — 256B-contiguous wave reads over q, gamma/beta in LDS,
//          8 qh-partials folded in k_final.

#define NB 4
#define CC 256
#define HW 4096
#define NQ0 8    // gemm loop-split (CMAX partials)
#define NQH 8    // pass2 q-splits (MAXV partials)

static constexpr float kEPS = 1e-8f;
static constexpr float kSIG = 0.1f + 1e-8f;

typedef __attribute__((ext_vector_type(8)))  short short8;
typedef __attribute__((ext_vector_type(16))) float f32x16;

// workspace layout (float units)
enum {
  OFF_MEAN = 0,                        // 256 channel means
  OFF_CMAX = 256,                      // NQ0*NB*HW colmax partials
  OFF_GB   = OFF_CMAX + NQ0*NB*HW,     // gamma[NB*HW], beta[NB*HW]
  OFF_MAXV = OFF_GB + 2*NB*HW,         // NQH*NB*HW maxv partials
  OFF_GT   = OFF_MAXV + NQH*NB*HW,     // NB*HW*CC bf16, fragment-tiled
  OFF_GI   = OFF_GT + NB*HW*CC/2,
  OFF_S    = OFF_GI + NB*HW*CC/2,      // NB*HW*HW bf16, TRANSPOSED [q][p]
  WS_FLOATS_FULL = OFF_S + NB*HW*HW/2
};

__device__ __forceinline__ ushort cvt_bf16(float x) {
  unsigned u = __float_as_uint(x);
  unsigned r = (u + 0x7fffu + ((u >> 16) & 1u)) >> 16;  // round-nearest-even
  return (ushort)r;
}
__device__ __forceinline__ float bf2f(ushort u) {
  return __uint_as_float((unsigned)u << 16);
}

__device__ __forceinline__ float blockSum256(float v) {
  __shared__ float sh[4];
  const int lane = threadIdx.x & 63, wv = threadIdx.x >> 6;
  #pragma unroll
  for (int o = 32; o > 0; o >>= 1) v += __shfl_down(v, o, 64);
  __syncthreads();
  if (lane == 0) sh[wv] = v;
  __syncthreads();
  return sh[0] + sh[1] + sh[2] + sh[3];
}

// K1: per-channel mean of featureT. grid=256
__global__ __launch_bounds__(256) void k_meanA(const float* __restrict__ fT,
                                               float* __restrict__ ws) {
  const int c = blockIdx.x, t = threadIdx.x;
  float s = 0.f;
  for (int n = 0; n < NB; ++n) {
    const float* p = fT + (size_t)(n*CC + c)*HW;
    #pragma unroll
    for (int k = 0; k < 16; ++k) s += p[k*256 + t];
  }
  const float tot = blockSum256(s);
  if (t == 0) ws[OFF_MEAN + c] = tot * (1.0f/16384.0f);
}

// K2: fused normalize + fragment-tiled bf16 write (verified R14 layout):
// offset_ushort(n, r32, kc) = ((n*128 + r32)*16 + kc)*512 + l*8
//   holds X[n][p = r32*32 + (l&31)][c = kc*16 + (l>>5)*8 + j], j<8.
// grid = 2 * NB * 128 = 1024 blocks.
__global__ __launch_bounds__(256) void k_prepA(const float* __restrict__ fT,
                                               const float* __restrict__ fI,
                                               float* __restrict__ ws) {
  __shared__ float stage[32][257];
  __shared__ float prt[8][32];
  __shared__ float sinv[32];
  const int t = threadIdx.x, l = t & 63;
  int bid = blockIdx.x;
  const int tensor = (bid >= 512); bid &= 511;
  const int n   = bid >> 7;
  const int r32 = bid & 127;
  const int p0  = r32 * 32;

  const float* __restrict__ src = tensor ? fI : fT;
  ushort* __restrict__ dst = (ushort*)(ws + (tensor ? OFF_GI : OFF_GT));
  const float* __restrict__ mean = ws + OFF_MEAN;

  const int pl = t & 31, cg = t >> 5;
  float acc = 0.f;
  #pragma unroll
  for (int i = 0; i < 32; ++i) {
    const int c = cg*32 + i;
    const float v = src[((size_t)(n*CC + c))*HW + p0 + pl] - mean[c];
    stage[pl][c] = v;
    acc += v*v;
  }
  prt[cg][pl] = acc;
  __syncthreads();
  if (t < 32) {
    float s = 0.f;
    #pragma unroll
    for (int g = 0; g < 8; ++g) s += prt[g][t];
    sinv[t] = 1.0f/(sqrtf(s) + kEPS);
  }
  __syncthreads();

  const int w = t >> 6, lhi = l >> 5, m = l & 31;
  const float iv = sinv[m];
  #pragma unroll
  for (int i = 0; i < 4; ++i) {
    const int kc = w*4 + i;
    const int cb = kc*16 + lhi*8;
    short8 o;
    #pragma unroll
    for (int j = 0; j < 8; ++j)
      ((ushort*)&o)[j] = cvt_bf16(stage[m][cb + j] * iv);
    *(short8*)(dst + (((size_t)(n*128 + r32)*16 + kc) << 9) + l*8) = o;
  }
}

// K3: single GEMM sweep + transposed bf16 S store (ushort4) + colmax.
// grid = NB*32strips*NQ0 = 1024 blocks, 4 blocks/CU.
__global__ __launch_bounds__(256, 4) void k_gemmA(
    const ushort* __restrict__ gA, const ushort* __restrict__ gB,
    float* __restrict__ ws)
{
  __shared__ ushort Ab[2][8192];     // double-buffered 32-row A tile (16KB)
  __shared__ float red2[128];

  const int t = threadIdx.x;
  const int w = t >> 6, l = t & 63;
  const int ln31 = l & 31, lhi = l >> 5;

  const int b = blockIdx.x;
  const int h = b & 7, sid = b >> 3;
  const int n = sid >> 5;
  const int col0 = (sid & 31) * 128;

  const ushort* __restrict__ gAn = gA + (size_t)(n*128 + h*16)*8192;

  // prologue staging: tile0 -> Ab[0]; tile1 -> pf
  short8 pf[4];
  #pragma unroll
  for (int i = 0; i < 4; ++i)
    pf[i] = *(const short8*)(gAn + (size_t)(i*256 + t)*8);
  #pragma unroll
  for (int i = 0; i < 4; ++i)
    *(short8*)&Ab[0][(i*256 + t)*8] = pf[i];
  #pragma unroll
  for (int i = 0; i < 4; ++i)
    pf[i] = *(const short8*)(gAn + 8192 + (size_t)(i*256 + t)*8);

  // B fragments: wave w owns col-tile RB
  const int RB = (col0 >> 5) + w;
  short8 breg[16];
  #pragma unroll
  for (int kc = 0; kc < 16; ++kc)
    breg[kc] = *(const short8*)(gB +
        (((size_t)(n*128 + RB)*16 + kc) << 9) + l*8);

  const int qc = col0 + w*32 + ln31;
  // S^T row base for this lane's column q=qc
  ushort* __restrict__ Srow =
      (ushort*)(ws + OFF_S) + (size_t)n*HW*HW + (size_t)qc*HW;

  float runl = -3.0e38f;

  for (int iter = 0; iter < 16; ++iter) {
    const int p = iter & 1;
    __syncthreads();
    if (iter + 1 < 16) {
      #pragma unroll
      for (int i = 0; i < 4; ++i)
        *(short8*)&Ab[p^1][(i*256 + t)*8] = pf[i];
      if (iter + 2 < 16) {
        const ushort* __restrict__ src = gAn + (size_t)(iter + 2)*8192;
        #pragma unroll
        for (int i = 0; i < 4; ++i)
          pf[i] = *(const short8*)(src + (size_t)(i*256 + t)*8);
      }
    }

    f32x16 acc;
    #pragma unroll
    for (int e = 0; e < 16; ++e) acc[e] = 0.f;
    #pragma unroll
    for (int kc = 0; kc < 16; ++kc) {
      const short8 a0 = *(const short8*)&Ab[p][kc*512 + l*8];
      acc = __builtin_amdgcn_mfma_f32_32x32x16_bf16(a0, breg[kc], acc, 0, 0, 0);
    }

    // epilogue: round -> packed ushort4 store into S^T, colmax over ROUNDED.
    // C/D map: row_local = (r&3) + 8*(r>>2) + 4*lhi; group g=r>>2 gives 4
    // consecutive rows -> one 8B store each.
    const int pb = h*512 + iter*32 + 4*lhi;
    #pragma unroll
    for (int g = 0; g < 4; ++g) {
      ushort4 u;
      u.x = cvt_bf16(acc[g*4 + 0]);
      u.y = cvt_bf16(acc[g*4 + 1]);
      u.z = cvt_bf16(acc[g*4 + 2]);
      u.w = cvt_bf16(acc[g*4 + 3]);
      *(ushort4*)(Srow + pb + 8*g) = u;
      runl = fmaxf(runl, fmaxf(fmaxf(bf2f(u.x), bf2f(u.y)),
                               fmaxf(bf2f(u.z), bf2f(u.w))));
    }
  }

  {
    const float o = __shfl_xor(runl, 32, 64);
    runl = fmaxf(runl, o);
  }
  if (l < 32) red2[w*32 + ln31] = runl;
  __syncthreads();
  if (t < 128)
    ws[OFF_CMAX + h*(NB*HW) + n*HW + col0 + t] = red2[t];
}

// K4: pass1 — Wsum per q over the WHOLE p range (contiguous S^T row reads),
// then gamma/beta written directly (k_gb fused away).
// grid = NB*128; block = 32 q rows; wave w owns rows w*8..w*8+7.
__global__ __launch_bounds__(256) void k_pass1A(float* __restrict__ ws) {
  const int t = threadIdx.x, w = t >> 6, l = t & 63;
  const int b = blockIdx.x;
  const int n = b >> 7, qg = b & 127;

  const ushort* __restrict__ S =
      (const ushort*)(ws + OFF_S) + (size_t)n*HW*HW;

  #pragma unroll
  for (int rr = 0; rr < 8; ++rr) {
    const int q = qg*32 + w*8 + rr;
    // alpha/beta from CMAX partials (broadcast loads, all lanes same addr)
    float cm = -3.0e38f;
    #pragma unroll
    for (int hh = 0; hh < NQ0; ++hh)
      cm = fmaxf(cm, ws[OFF_CMAX + hh*(NB*HW) + n*HW + q]);
    const float inv2d = 1.0f/(2.0f*(0.5f*(1.0f - cm) + kEPS));
    const float beta  = inv2d / kSIG;
    const float alpha = (1.0f - inv2d) / kSIG;

    const ushort* __restrict__ row = S + (size_t)q*HW;
    float acc = 0.f;
    #pragma unroll 4
    for (int it = 0; it < 16; ++it) {
      const ushort4 u = *(const ushort4*)(row + it*256 + l*4);
      acc += __expf(fmaf(beta, bf2f(u.x), alpha));
      acc += __expf(fmaf(beta, bf2f(u.y), alpha));
      acc += __expf(fmaf(beta, bf2f(u.z), alpha));
      acc += __expf(fmaf(beta, bf2f(u.w), alpha));
    }
    #pragma unroll
    for (int o = 32; o > 0; o >>= 1) acc += __shfl_down(acc, o, 64);
    if (l == 0) {
      ws[OFF_GB + n*HW + q]         = alpha - logf(acc + kEPS);  // gamma
      ws[OFF_GB + NB*HW + n*HW + q] = beta;
    }
  }
}

// K5: pass2 — maxv partials: max over a 512-q slab of (gamma_q + beta_q s).
// grid = NB * 8 pslabs * NQH = 256 blocks; block covers 512 p x 512 q.
// thread t owns p = ps*512 + 2t (ushort2); wave reads 256B contiguous.
__global__ __launch_bounds__(256) void k_pass2A(float* __restrict__ ws) {
  __shared__ float gq[512], bq[512];
  const int t = threadIdx.x;
  const int b = blockIdx.x;
  const int qh = b & 7, rest = b >> 3;
  const int n = rest >> 3, ps = rest & 7;

  #pragma unroll
  for (int i = 0; i < 2; ++i) {
    const int r = i*256 + t;
    gq[r] = ws[OFF_GB + n*HW + qh*512 + r];
    bq[r] = ws[OFF_GB + NB*HW + n*HW + qh*512 + r];
  }
  __syncthreads();

  const ushort* __restrict__ S =
      (const ushort*)(ws + OFF_S) + (size_t)n*HW*HW + (size_t)qh*512*HW
      + ps*512 + 2*t;
  float m0 = -3.0e38f, m1 = -3.0e38f;
  #pragma unroll 4
  for (int q = 0; q < 512; ++q) {
    const ushort2 u = *(const ushort2*)(S + (size_t)q*HW);
    m0 = fmaxf(m0, fmaf(bq[q], bf2f(u.x), gq[q]));
    m1 = fmaxf(m1, fmaf(bq[q], bf2f(u.y), gq[q]));
  }
  float2 o; o.x = m0; o.y = m1;
  *(float2*)&ws[OFF_MAXV + qh*(NB*HW) + n*HW + ps*512 + 2*t] = o;
}

// K6: final loss. one block. folds the NQH maxv partials.
__global__ __launch_bounds__(256) void k_finalA(const float* __restrict__ ws,
                                                float* __restrict__ out) {
  const int t = threadIdx.x;
  float loss = 0.f;
  for (int n = 0; n < NB; ++n) {
    float s = 0.f;
    for (int k = 0; k < 16; ++k) {
      const int idx = n*HW + k*256 + t;
      float mv = ws[OFF_MAXV + idx];
      #pragma unroll
      for (int qh = 1; qh < NQH; ++qh)
        mv = fmaxf(mv, ws[OFF_MAXV + qh*(NB*HW) + idx]);
      s += __expf(mv);
    }
    const float tot = blockSum256(s);
    loss += -logf(tot*(1.0f/4096.0f) + kEPS);
  }
  if (t == 0) out[0] = loss*0.25f;
}

extern "C" void kernel_launch(void* const* d_in, const int* in_sizes, int n_in,
                              void* d_out, int out_size, void* d_ws, size_t ws_size,
                              hipStream_t stream) {
  const float* fT = (const float*)d_in[0];
  const float* fI = (const float*)d_in[1];
  float* out = (float*)d_out;
  float* ws  = (float*)d_ws;

  const size_t need_full = (size_t)WS_FLOATS_FULL * sizeof(float);
  if (ws_size < need_full) return;  // ws measured 256 MB (R2); need ~152 MB

  const ushort* GT = (const ushort*)(ws + OFF_GT);
  const ushort* GI = (const ushort*)(ws + OFF_GI);
  k_meanA <<<256,  256, 0, stream>>>(fT, ws);
  k_prepA <<<1024, 256, 0, stream>>>(fT, fI, ws);
  k_gemmA <<<1024, 256, 0, stream>>>(GT, GI, ws);   // S^T + colmax partials
  k_pass1A<<<512,  256, 0, stream>>>(ws);           // gamma/beta direct
  k_pass2A<<<256,  256, 0, stream>>>(ws);           // maxv partials
  k_finalA<<<1,    256, 0, stream>>>(ws, out);
}